// Round 13
// baseline (95.936 us; speedup 1.0000x reference)
//
#include <hip/hip_runtime.h>

typedef short bf16x8 __attribute__((ext_vector_type(8)));
typedef float f32x16 __attribute__((ext_vector_type(16)));

// round-to-nearest-even fp32 -> bf16 (bits)
static __device__ __forceinline__ unsigned short f2bf(float x) {
    unsigned u = __builtin_bit_cast(unsigned, x);
    unsigned r = (u + 0x7FFFu + ((u >> 16) & 1u)) >> 16;
    return (unsigned short)r;
}
static __device__ __forceinline__ float bf2f(unsigned short h) {
    unsigned u = (unsigned)h << 16;
    return __builtin_bit_cast(float, u);
}

// Workspace (shorts): A1[P*16] | A2[P*16] | B1[P*16] | B2[P*16]

// Kernel 1: per point p build MFMA K-vectors (bf16, hi/lo split) for two grams:
//   gram1: denom = 1 + s_i + s_j - 2<c_i,c_j>;  gram2: dot = <n_i,n_j>
// 32x32x16 fragment layout (verified R5-R12, absmax 0.0): point p -> tile=p>>5,
// m=p&31; k0..7 chunk -> lane m, k8..15 -> lane 32+m.
// Targets carry NEGATED normals (folds e_ss - 2 e_st + e_tt into one sum).
__global__ void dc_pack(const float* __restrict__ verts,
                        const float* __restrict__ tnorm,
                        const float* __restrict__ tcent,
                        const int* __restrict__ idx,
                        unsigned short* __restrict__ ws,
                        float* __restrict__ out,
                        int N, int M) {
    int p = blockIdx.x * blockDim.x + threadIdx.x;
    if (p == 0) out[0] = 0.0f;
    int P = N + M;
    if (p >= P) return;

    float cx, cy, cz, nx, ny, nz;
    if (p < N) {
        int i0 = idx[3 * p + 0], i1 = idx[3 * p + 1], i2 = idx[3 * p + 2];
        float ax = verts[3 * i0], ay = verts[3 * i0 + 1], az = verts[3 * i0 + 2];
        float bx = verts[3 * i1], by = verts[3 * i1 + 1], bz = verts[3 * i1 + 2];
        float qx = verts[3 * i2], qy = verts[3 * i2 + 1], qz = verts[3 * i2 + 2];
        float ux = ax - bx, uy = ay - by, uz = az - bz;
        float vx = qx - bx, vy = qy - by, vz = qz - bz;
        nx = 0.5f * (uy * vz - uz * vy);
        ny = 0.5f * (uz * vx - ux * vz);
        nz = 0.5f * (ux * vy - uy * vx);
        cx = (ax + bx + qx) * (1.0f / 3.0f);
        cy = (ay + by + qy) * (1.0f / 3.0f);
        cz = (az + bz + qz) * (1.0f / 3.0f);
    } else {
        int t = p - N;
        cx = tcent[3 * t]; cy = tcent[3 * t + 1]; cz = tcent[3 * t + 2];
        nx = -tnorm[3 * t]; ny = -tnorm[3 * t + 1]; nz = -tnorm[3 * t + 2];
    }

    unsigned short chx = f2bf(cx), chy = f2bf(cy), chz = f2bf(cz);
    unsigned short clx = f2bf(cx - bf2f(chx));
    unsigned short cly = f2bf(cy - bf2f(chy));
    unsigned short clz = f2bf(cz - bf2f(chz));
    unsigned short nhx = f2bf(nx), nhy = f2bf(ny), nhz = f2bf(nz);
    unsigned short nlx = f2bf(nx - bf2f(nhx));
    unsigned short nly = f2bf(ny - bf2f(nhy));
    unsigned short nlz = f2bf(nz - bf2f(nhz));
    float ex = bf2f(chx) + bf2f(clx);
    float ey = bf2f(chy) + bf2f(cly);
    float ez = bf2f(chz) + bf2f(clz);
    float s = ex * ex + ey * ey + ez * ez;
    unsigned short sh = f2bf(s), sl = f2bf(s - bf2f(sh));
    unsigned short m2hx = f2bf(-2.0f * bf2f(chx)), m2hy = f2bf(-2.0f * bf2f(chy)), m2hz = f2bf(-2.0f * bf2f(chz));
    unsigned short m2lx = f2bf(-2.0f * bf2f(clx)), m2ly = f2bf(-2.0f * bf2f(cly)), m2lz = f2bf(-2.0f * bf2f(clz));
    const unsigned short one = 0x3F80;

    __align__(16) unsigned short A1v[16] = {
        m2hx, m2hy, m2hz,  m2hx, m2hy, m2hz,  m2lx, m2ly, m2lz,
        sh, sl,  one, one,  one,  0, 0 };
    __align__(16) unsigned short B1v[16] = {
        chx, chy, chz,  clx, cly, clz,  chx, chy, chz,
        one, one,  sh, sl,  one,  0, 0 };
    __align__(16) unsigned short A2v[16] = {
        nhx, nhy, nhz,  nhx, nhy, nhz,  nlx, nly, nlz,
        0, 0, 0, 0, 0, 0, 0 };
    __align__(16) unsigned short B2v[16] = {
        nhx, nhy, nhz,  nlx, nly, nlz,  nhx, nhy, nhz,
        0, 0, 0, 0, 0, 0, 0 };

    size_t arr = (size_t)P * 16;
    unsigned short* A1 = ws;
    unsigned short* A2 = ws + arr;
    unsigned short* B1 = ws + 2 * arr;
    unsigned short* B2 = ws + 3 * arr;

    int tile = p >> 5, m = p & 31;
    size_t lo = ((size_t)tile * 64 + m) * 8;       // k0..7 -> lane m
    size_t hi = lo + 32 * 8;                       // k8..15 -> lane 32+m

    *(uint4*)(A1 + lo) = *(const uint4*)&A1v[0];
    *(uint4*)(A1 + hi) = *(const uint4*)&A1v[8];
    *(uint4*)(A2 + lo) = *(const uint4*)&A2v[0];
    *(uint4*)(A2 + hi) = *(const uint4*)&A2v[8];
    *(uint4*)(B1 + lo) = *(const uint4*)&B1v[0];
    *(uint4*)(B1 + hi) = *(const uint4*)&B1v[8];
    *(uint4*)(B2 + lo) = *(const uint4*)&B2v[0];
    *(uint4*)(B2 + hi) = *(const uint4*)&B2v[8];
}

// 4-way batched reciprocal: sum of 4 x/a terms via 1 rcp (trans-pipe 4x cut).
static __device__ __forceinline__ void acc4(float4& part, const f32x16& d1, const f32x16& d2) {
#pragma unroll
    for (int g = 0; g < 4; ++g) {
        const int r = 4 * g;
        float p01 = d1[r] * d1[r + 1];
        float p23 = d1[r + 2] * d1[r + 3];
        float n01 = fmaf(d2[r], d1[r + 1], d2[r + 1] * d1[r]);
        float n23 = fmaf(d2[r + 2], d1[r + 3], d2[r + 3] * d1[r + 2]);
        float t   = p01 * p23;
        float num = fmaf(n01, p23, n23 * p01);
        (&part.x)[g] = fmaf(num, __builtin_amdgcn_rcpf(t), (&part.x)[g]);
    }
}

// Kernel 2: single-row circular sweep at FULL occupancy (8 waves/SIMD).
// Row I, window j in [I+1, I+256] (mod nT=512):
//   full = sum_I [ 2*sum_{d=1..256} T(I,I+d) + T(I,I) - T(I,I+256) ]
// R5-R12 all ran ~4 waves/SIMD and every intra-wave restructuring was
// neutral at ~4x pipe-demand wall -> latency-stall-bound, fixable only by
// TLP. Single-row body needs ~56 regs (a 8 + b 8 + d 32 + acc/addr), under
// the 64-VGPR / 8-wave cliff (m69). 512 rows x 16 chunks = 8192 waves =
// 2048 blocks = exactly 8 blocks/CU, ONE uniform batch. Worst case (only
// 4/CU granted): exactly 2 uniform batches ~ neutral vs R10.
__global__ __launch_bounds__(256, 8) void dc_pair_mfma(
    const unsigned short* __restrict__ ws, float* __restrict__ out, int P) {
    __shared__ float wsum[4];

    const int nT = P >> 5;                     // 512
    size_t arr = (size_t)P * 16;
    const unsigned short* A1 = ws;
    const unsigned short* A2 = ws + arr;
    const unsigned short* B1 = ws + 2 * arr;
    const unsigned short* B2 = ws + 3 * arr;

    int tid = threadIdx.x;
    int lane = tid & 63, wv = tid >> 6;
    int gi = blockIdx.x * 4 + wv;              // 0..8191
    int I = gi >> 4, c = gi & 15;              // row, chunk

    const size_t lo = (size_t)lane * 8;

    bf16x8 a1 = *(const bf16x8*)(A1 + (size_t)I * 512 + lo);
    bf16x8 a2 = *(const bf16x8*)(A2 + (size_t)I * 512 + lo);

    const f32x16 zero = {0.f,0.f,0.f,0.f,0.f,0.f,0.f,0.f,0.f,0.f,0.f,0.f,0.f,0.f,0.f,0.f};
    float4 partA = make_float4(0.f, 0.f, 0.f, 0.f);

    // chunk window: 16 j-tiles at offsets d = 16c+1 .. 16c+16 (raw max 767)
    int js = I + 1 + 16 * c;
#pragma unroll 1
    for (int it = 0; it < 16; ++it) {
        int j = js + it; if (j >= nT) j -= nT;         // wave-uniform SALU
        size_t o = (size_t)j * 512 + lo;
        bf16x8 b1 = *(const bf16x8*)(B1 + o);
        bf16x8 b2 = *(const bf16x8*)(B2 + o);
        f32x16 d1 = __builtin_amdgcn_mfma_f32_32x32x16_bf16(a1, b1, zero, 0, 0, 0);
        f32x16 d2 = __builtin_amdgcn_mfma_f32_32x32x16_bf16(a2, b2, zero, 0, 0, 0);
        acc4(partA, d1, d2);
    }

    float s = 2.0f * (partA.x + partA.y + partA.z + partA.w);

    // corrections (outside the hot loop, registers reusable):
    //   chunk 0:  +T(I,I)      chunk 15: -T(I,I+256)
    if (c == 0 || c == 15) {
        int jm;
        if (c == 0) jm = I;
        else { jm = I + 256; if (jm >= nT) jm -= nT; }
        size_t o = (size_t)jm * 512 + lo;
        bf16x8 b1 = *(const bf16x8*)(B1 + o);
        bf16x8 b2 = *(const bf16x8*)(B2 + o);
        f32x16 d1 = __builtin_amdgcn_mfma_f32_32x32x16_bf16(a1, b1, zero, 0, 0, 0);
        f32x16 d2 = __builtin_amdgcn_mfma_f32_32x32x16_bf16(a2, b2, zero, 0, 0, 0);
        float4 corr = make_float4(0.f, 0.f, 0.f, 0.f);
        acc4(corr, d1, d2);
        float cs = corr.x + corr.y + corr.z + corr.w;
        s += (c == 0) ? cs : -cs;
    }

#pragma unroll
    for (int off = 32; off > 0; off >>= 1) s += __shfl_down(s, off, 64);
    if (lane == 0) wsum[wv] = s;
    __syncthreads();
    if (tid == 0) {
        float t = wsum[0] + wsum[1] + wsum[2] + wsum[3];
        atomicAdd(out, t);
    }
}

extern "C" void kernel_launch(void* const* d_in, const int* in_sizes, int n_in,
                              void* d_out, int out_size, void* d_ws, size_t ws_size,
                              hipStream_t stream) {
    const float* verts = (const float*)d_in[0];   // (V,3) f32
    const float* tnorm = (const float*)d_in[1];   // (M,3) f32
    const float* tcent = (const float*)d_in[2];   // (M,3) f32
    const int*   sidx  = (const int*)d_in[3];     // (N,3) i32

    int M = in_sizes[1] / 3;
    int N = in_sizes[3] / 3;
    int P = N + M;                                // 16384

    unsigned short* ws = (unsigned short*)d_ws;   // A1|A2|B1|B2 = 4 MB
    float* out = (float*)d_out;

    int bblocks = (P + 255) / 256;
    dc_pack<<<bblocks, 256, 0, stream>>>(verts, tnorm, tcent, sidx, ws, out, N, M);

    // 512 rows x 16 chunks = 8192 waves = 2048 blocks = 8/CU, one batch
    dc_pair_mfma<<<2048, 256, 0, stream>>>(ws, out, P);
}